// Round 6
// baseline (9934.384 us; speedup 1.0000x reference)
//
#include <hip/hip_runtime.h>

typedef unsigned short u16;
typedef unsigned int   u32;

typedef __bf16 bf16x8 __attribute__((ext_vector_type(8)));
typedef float  f32x4  __attribute__((ext_vector_type(4)));

#define B_    32
#define S_    512
#define I_    512
#define H_    1024
#define NBLK  128                 // blocks; each owns H_/NBLK = 8 hidden units
#define HU    8
#define MAGIC 0x13579BDFu

__device__ __forceinline__ float sigmoid_(float x) {
    return 1.0f / (1.0f + __expf(-x));
}
__device__ __forceinline__ float tanh_(float x) {
    return 2.0f / (1.0f + __expf(-2.0f * x)) - 1.0f;
}

// Persistent LSTM (fp32 I/O, bf16 MFMA compute).
// h-data plan (measured-correct in round 5): producer sc1 write-through of
// fp32 h into out[] (hidden_seq IS the ring; every line written once, read
// once -> no stale-L2 hazard for plain cacheable consumer loads; startup
// buffer_wbl2+buffer_inv clears the harness's poison memset lines).
// Signal plan (new): ONE agent atomicAdd per block per step on a single
// counter + ONE polling thread per block with s_sleep backoff. ~128 adds and
// a few hundred polls per step vs round 5's ~10^5-10^6 sc1 poll loads -- the
// poll storm was saturating the IC fabric (round 5 post-mortem).
__global__ void __launch_bounds__(256, 1)
lstm_kernel(const float* __restrict__ X,
            const float* __restrict__ w_i, const float* __restrict__ u_i, const float* __restrict__ b_i,
            const float* __restrict__ w_f, const float* __restrict__ u_f, const float* __restrict__ b_f,
            const float* __restrict__ w_c, const float* __restrict__ u_c, const float* __restrict__ b_c,
            const float* __restrict__ w_o, const float* __restrict__ u_o, const float* __restrict__ b_o,
            float* __restrict__ out, u32* __restrict__ barflag, u32* __restrict__ barcnt)
{
    __shared__ float gbuf[32 * 33];   // raw gates, +1 col pad

    const int tid  = threadIdx.x;
    const int wave = tid >> 6;
    const int lane = tid & 63;
    const int rt   = wave >> 1;       // row tile (batch 16*rt..)
    const int ct   = wave & 1;        // col tile (gate cols 16*ct..)
    const int quad = lane >> 4;
    const int l16  = lane & 15;
    const int hu0  = blockIdx.x * HU;

    // ---- B-operand fragments into registers (once), fp32 -> bf16 ----
    // block-local gate col: 0..31 = gate g (i,f,c,o) * 8 + unit u
    const int col = ct * 16 + l16;
    const int g   = col >> 3;
    const int u   = col & 7;
    const float* Ucol = ((g == 0) ? u_i : (g == 1) ? u_f : (g == 2) ? u_c : u_o) + hu0 + u;
    const float* Wcol = ((g == 0) ? w_i : (g == 1) ? w_f : (g == 2) ? w_c : w_o) + hu0 + u;

    bf16x8 bfr[48];                   // B[k = kb*32 + quad*8 + j][col]
    #pragma unroll
    for (int kb = 0; kb < 32; ++kb) { // K 0..1023: U rows
        #pragma unroll
        for (int j = 0; j < 8; ++j) {
            int k = kb * 32 + quad * 8 + j;
            bfr[kb][j] = (__bf16)Ucol[k * H_];
        }
    }
    #pragma unroll
    for (int kb = 32; kb < 48; ++kb) { // K 1024..1535: W rows
        #pragma unroll
        for (int j = 0; j < 8; ++j) {
            int k = kb * 32 + quad * 8 + j - 1024;
            bfr[kb][j] = (__bf16)Wcol[k * H_];
        }
    }

    // ---- update-phase ownership: thread -> (batch ub, unit uu) ----
    const int ub   = tid >> 3;        // batch 0..31
    const int uu   = tid & 7;         // unit  0..7
    const int unit = hu0 + uu;

    const float bia = b_i[unit];
    const float bif = b_f[unit];
    const float bic = b_c[unit];
    const float bio = b_o[unit];
    float cstate = 0.0f;

    const int    arow = rt * 16 + l16;                              // batch row fed to A
    const float* xrow = X   + (size_t)arow * (S_ * I_) + quad * 8;
    const float* hrow = out + (size_t)arow * (S_ * H_) + quad * 8;  // fp32 h ring

    // ---- startup: flush local L2 of the harness's dirty poison lines ----
    asm volatile("s_waitcnt vmcnt(0)\n\t"
                 "buffer_wbl2 sc1\n\t"
                 "s_waitcnt vmcnt(0)\n\t"
                 "buffer_inv sc1" ::: "memory");
    for (int i = 0; i < 96; ++i) __builtin_amdgcn_s_sleep(7);   // ~18 us settle

    // ---- barrier init handshake (ws is poison-filled each launch) ----
    if (blockIdx.x == 0 && tid == 0) {
        __hip_atomic_store(barcnt, 0u, __ATOMIC_RELAXED, __HIP_MEMORY_SCOPE_AGENT);
        __hip_atomic_store(barflag, MAGIC, __ATOMIC_RELEASE, __HIP_MEMORY_SCOPE_AGENT);
    }
    if (tid == 0) {
        while (__hip_atomic_load(barflag, __ATOMIC_ACQUIRE, __HIP_MEMORY_SCOPE_AGENT) != MAGIC)
            __builtin_amdgcn_s_sleep(4);
    }
    __syncthreads();

    for (int t = 0; t < S_; ++t) {
        // ---- x_t @ W: h-independent, fills the wait window ----
        f32x4 acc = {0.f, 0.f, 0.f, 0.f};
        const float* xk = xrow + (size_t)t * I_;
        #pragma unroll
        for (int kb = 0; kb < 16; ++kb) {
            f32x4 lo = *(const f32x4*)(xk + kb * 32);
            f32x4 hi = *(const f32x4*)(xk + kb * 32 + 4);
            bf16x8 a;
            a[0] = (__bf16)lo[0]; a[1] = (__bf16)lo[1];
            a[2] = (__bf16)lo[2]; a[3] = (__bf16)lo[3];
            a[4] = (__bf16)hi[0]; a[5] = (__bf16)hi[1];
            a[6] = (__bf16)hi[2]; a[7] = (__bf16)hi[3];
            acc = __builtin_amdgcn_mfma_f32_16x16x32_bf16(a, bfr[32 + kb], acc, 0, 0, 0);
        }

        if (t > 0) {
            // ---- wait: single poller per block on the step counter ----
            if (tid == 0) {
                while (__hip_atomic_load(barcnt, __ATOMIC_RELAXED,
                                         __HIP_MEMORY_SCOPE_AGENT) < (u32)(NBLK * t))
                    __builtin_amdgcn_s_sleep(4);
            }
            __syncthreads();   // release; also compiler memory barrier (no hoist)

            // ---- h(t-1) @ U: plain cacheable fp32 loads from out ----
            const float* hk = hrow + (size_t)(t - 1) * H_;
            #pragma unroll
            for (int kb = 0; kb < 32; ++kb) {
                f32x4 lo = *(const f32x4*)(hk + kb * 32);
                f32x4 hi = *(const f32x4*)(hk + kb * 32 + 4);
                bf16x8 a;
                a[0] = (__bf16)lo[0]; a[1] = (__bf16)lo[1];
                a[2] = (__bf16)lo[2]; a[3] = (__bf16)lo[3];
                a[4] = (__bf16)hi[0]; a[5] = (__bf16)hi[1];
                a[6] = (__bf16)hi[2]; a[7] = (__bf16)hi[3];
                acc = __builtin_amdgcn_mfma_f32_16x16x32_bf16(a, bfr[kb], acc, 0, 0, 0);
            }
        }
        // (t == 0: h0 = 0 contributes nothing — skip wait and h@U entirely)

        // C/D layout: D[row = quad*4 + r][col = lane&15] (+16 per tile)
        {
            const int r0 = rt * 16 + quad * 4;
            #pragma unroll
            for (int r = 0; r < 4; ++r)
                gbuf[(r0 + r) * 33 + col] = acc[r];
        }
        __syncthreads();

        // gates -> c,h update (c stays in an fp32 register all 512 steps)
        {
            float gi = gbuf[ub * 33 + uu]      + bia;
            float gf = gbuf[ub * 33 + 8 + uu]  + bif;
            float gc = gbuf[ub * 33 + 16 + uu] + bic;
            float go = gbuf[ub * 33 + 24 + uu] + bio;
            float it  = sigmoid_(gi);
            float ft  = sigmoid_(gf);
            float ctl = tanh_(gc);
            float ot  = sigmoid_(go);
            cstate = ft * cstate + it * ctl;
            float h = ot * tanh_(cstate);

            // h -> out (hidden_seq), sc1 write-through to IC (consumer-visible)
            u32* hp = (u32*)(out + (size_t)ub * (S_ * H_) + (size_t)t * H_ + unit);
            __hip_atomic_store(hp, __builtin_bit_cast(u32, h),
                               __ATOMIC_RELAXED, __HIP_MEMORY_SCOPE_AGENT);
            if (t == S_ - 1) {
                out[(size_t)B_ * S_ * H_ + ub * H_ + unit] = h;                  // h_t
                out[(size_t)B_ * S_ * H_ + B_ * H_ + ub * H_ + unit] = cstate;   // c_t
            }
        }
        asm volatile("s_waitcnt vmcnt(0)" ::: "memory");   // this wave's h acked in IC
        __syncthreads();                                   // all 4 waves drained
        if (tid == 0)
            __hip_atomic_fetch_add(barcnt, 1u, __ATOMIC_RELAXED, __HIP_MEMORY_SCOPE_AGENT);
        __syncthreads();                                   // gbuf WAR for next step
    }
}

extern "C" void kernel_launch(void* const* d_in, const int* in_sizes, int n_in,
                              void* d_out, int out_size, void* d_ws, size_t ws_size,
                              hipStream_t stream) {
    const float* X   = (const float*)d_in[0];
    const float* w_i = (const float*)d_in[1];
    const float* u_i = (const float*)d_in[2];
    const float* b_i = (const float*)d_in[3];
    const float* w_f = (const float*)d_in[4];
    const float* u_f = (const float*)d_in[5];
    const float* b_f = (const float*)d_in[6];
    const float* w_c = (const float*)d_in[7];
    const float* u_c = (const float*)d_in[8];
    const float* b_c = (const float*)d_in[9];
    const float* w_o = (const float*)d_in[10];
    const float* u_o = (const float*)d_in[11];
    const float* b_o = (const float*)d_in[12];
    float* out = (float*)d_out;

    // d_ws: [0,4) barrier init flag; [128,132) step counter (separate line).
    u32* barflag = (u32*)d_ws;
    u32* barcnt  = (u32*)((char*)d_ws + 128);

    hipLaunchKernelGGL(lstm_kernel, dim3(NBLK), dim3(256), 0, stream,
                       X, w_i, u_i, b_i, w_f, u_f, b_f, w_c, u_c, b_c,
                       w_o, u_o, b_o, out, barflag, barcnt);
}